// Round 1
// 519.141 us; speedup vs baseline: 1.0915x; 1.0915x over previous
//
#include <hip/hip_runtime.h>
#include <hip/hip_bf16.h>

// Problem constants
#define NB    1024   // batch
#define SEQ   512    // max seq len
#define DIM   128    // embedding dim (D)
#define HID   128    // hidden (H)
#define NOPS  16     // OPS
#define FEAT  144    // H + OPS
#define BQ    4      // samples per workgroup
#define AST   144    // sample stride inside a slot (bf16): breaks pow-2 bank strides
#define XST   578    // x slot stride (bf16) = 289 dwords, odd mod 32 -> ~2-way frag reads

typedef __bf16 bf16x8 __attribute__((ext_vector_type(8)));
typedef float  floatx4 __attribute__((ext_vector_type(4)));

__device__ __forceinline__ float fsig(float x)  { return 1.0f / (1.0f + __expf(-x)); }
__device__ __forceinline__ float ftanhf(float x){ return 2.0f / (1.0f + __expf(-2.0f * x)) - 1.0f; }

// LDS-only barrier: drains lgkmcnt (all cross-wave traffic is LDS), leaves
// global gathers in flight.
__device__ __forceinline__ void block_sync_lds() {
    asm volatile("s_waitcnt lgkmcnt(0)\n\ts_barrier" ::: "memory");
}

// One WG = 512 threads (8 waves) owns BQ=4 samples. Wave w owns unit-chunk w
// for all 4 gate types (gates consumed in-register). 4-STEP X-PACKING: one
// MFMA block per superstep computes x-gates for 4 samples x 4 timesteps
// (A row = sample*4 + off); C/D row quad*4+r -> x-gate(sample=quad, ts+r, uu)
// lands in lane (quad,lrow) reg r. In-loop serial MFMAs are h-part only
// (16/wave/step, fed C=xg directly -> no acc copies, no bias splats, no gate
// extraction selects). 8 rotating x-slots (stride 578 = odd dwords: ~2-way
// bank access on packed frag reads). One LDS barrier per step; h
// double-buffered by step parity (compile-time via 4x unroll).
//
// R5 (this round): kill the per-step dependent global->global chain.
//   (a) tokens staged to LDS once (8 KB, coalesced int4); per-step token is a
//       same-address LDS broadcast read, prefetched 1 step ahead into `tk`.
//   (b) embedding gather prefetch deepened 1 step -> 2 steps via parity pair
//       e0/e1 selected by compile-time OFF&1 (no v_mov shift, which would
//       force the vmcnt wait one step early). Gather latency (~600-900 cy,
//       L3/HBM) now has >= 2 full steps to complete off the critical path.
__global__ __launch_bounds__(512, 2)
void lstm_fused(const int* __restrict__ tokens, const int* __restrict__ lengths,
                const float* __restrict__ onehot, const float* __restrict__ emb,
                const float* __restrict__ Wih, const float* __restrict__ Whh,
                const float* __restrict__ bih, const float* __restrict__ bhh,
                const float* __restrict__ h0, const float* __restrict__ c0,
                const float* __restrict__ linW, const float* __restrict__ linb,
                float* __restrict__ out)
{
    __shared__ __align__(16) __bf16 xbuf[8 * XST];        // 8 rotating x slots
    __shared__ __align__(16) __bf16 hbuf[2 * BQ * AST];   // h, parity by t&1
    __shared__ __align__(16) float  hlbuf[BQ * HID];
    __shared__ __align__(16) int    tkbuf[BQ * SEQ];      // all tokens for the 4 samples

    const int tid  = threadIdx.x;
    const int wave = tid >> 6;
    const int lane = tid & 63;
    const int quad = lane >> 4;
    const int lrow = lane & 15;
    const int bid  = blockIdx.x;

    // ---- Weight B-fragments in registers (loaded once). ----
    // B-layout (16x16x32): lane holds B[k=quad*8+j][n=lrow].
    bf16x8 wfx[4][4], wfh[4][4];
#pragma unroll
    for (int gt = 0; gt < 4; ++gt) {
        const int g = gt * 128 + wave * 16 + lrow;
#pragma unroll
        for (int kt = 0; kt < 4; ++kt) {
            const float* sx = Wih + g * DIM + kt * 32 + quad * 8;
            const float* sh = Whh + g * HID + kt * 32 + quad * 8;
            float4 a = *(const float4*)(sx);
            float4 b = *(const float4*)(sx + 4);
            bf16x8 v;
            v[0] = (__bf16)a.x; v[1] = (__bf16)a.y; v[2] = (__bf16)a.z; v[3] = (__bf16)a.w;
            v[4] = (__bf16)b.x; v[5] = (__bf16)b.y; v[6] = (__bf16)b.z; v[7] = (__bf16)b.w;
            wfx[gt][kt] = v;
            a = *(const float4*)(sh);
            b = *(const float4*)(sh + 4);
            v[0] = (__bf16)a.x; v[1] = (__bf16)a.y; v[2] = (__bf16)a.z; v[3] = (__bf16)a.w;
            v[4] = (__bf16)b.x; v[5] = (__bf16)b.y; v[6] = (__bf16)b.z; v[7] = (__bf16)b.w;
            wfh[gt][kt] = v;
        }
    }

    // ---- Per-lane state: sample = quad, unit = uu = wave*16 + lrow ----
    const int uu = wave * 16 + lrow;
    const int bq = bid * BQ + quad;
    int lenq = lengths[bq]; if (lenq < 1) lenq = 1;
    const int tlast = lenq - 1;

    int Lmax = 0;
#pragma unroll
    for (int s2 = 0; s2 < BQ; ++s2) {
        int l2 = lengths[bid * BQ + s2]; if (l2 < 1) l2 = 1;
        Lmax = (l2 > Lmax) ? l2 : Lmax;
    }

    // persistent bias C-registers: accx chains start from these (no splats)
    floatx4 biasC[4];
#pragma unroll
    for (int gt = 0; gt < 4; ++gt) {
        const float bgt = bih[gt * 128 + uu] + bhh[gt * 128 + uu];
        floatx4 a0 = {bgt, bgt, bgt, bgt};
        biasC[gt] = a0;
    }

    float c  = c0[uu];
    float hl = 0.0f;

    // ---- Staging thread layout: m = tid>>7 (sample), u = tid&127 (unit) ----
    const int m  = tid >> 7;
    const int u  = tid & 127;
    const int bm = bid * BQ + m;
    const int sm = m * AST + u;

    // Stage ALL tokens for this WG's 4 samples into LDS (one int4 / thread,
    // fully coalesced). Removes the per-step global token load from the
    // token->emb dependent chain.
    {
        const int4 tv = *(const int4*)(tokens + (size_t)bid * (BQ * SEQ) + tid * 4);
        *(int4*)(&tkbuf[tid * 4]) = tv;
    }

    hbuf[sm] = (__bf16)h0[u];
    const int* tokm = tokens + (size_t)bm * SEQ;
#pragma unroll
    for (int k = 0; k <= 4; ++k) {   // stage x(0..4) into slots 0..4
        float ek = emb[(size_t)tokm[k] * DIM + u];
        xbuf[k * XST + sm] = (__bf16)fmaxf(ek, 0.0f);
    }
    // gather pipeline, 2 steps deep: e0 feeds x(5) at step 0, e1 feeds x(6)
    // at step 1; tk holds token for step 0's gather (x(7)).
    float e0 = emb[(size_t)tokm[5] * DIM + u];
    float e1 = emb[(size_t)tokm[6] * DIM + u];
    int   tk = tokm[7];

    // frag pointers
    const int xfbase = (lrow & 3) * XST + (lrow >> 2) * AST + quad * 8;
    const __bf16* const xfp[2] = { &xbuf[xfbase], &xbuf[4 * XST + xfbase] };
    const int habase = (lrow >> 2) * AST + quad * 8;
    const __bf16* const hf[2] = { &hbuf[habase], &hbuf[BQ * AST + habase] };
    __bf16* const hw[2] = { &hbuf[quad * AST + uu], &hbuf[BQ * AST + quad * AST + uu] };
    __bf16* const xw = &xbuf[sm];

    __syncthreads();   // x(0..4), h(0), tokens staged

    // xg[gt][r] = bias + x(ts+r)@W_ih^T for (sample quad, unit uu)
    floatx4 xg[4];
#define XBLOCK(G) do {                                                               \
        bf16x8 af_[4];                                                               \
        _Pragma("unroll") for (int kt = 0; kt < 4; ++kt)                             \
            af_[kt] = *(const bf16x8*)(xfp[G] + kt * 32);                            \
        _Pragma("unroll") for (int gt = 0; gt < 4; ++gt)                             \
            xg[gt] = __builtin_amdgcn_mfma_f32_16x16x32_bf16(af_[0], wfx[gt][0], biasC[gt], 0, 0, 0); \
        _Pragma("unroll") for (int kt = 1; kt < 4; ++kt)                             \
            _Pragma("unroll") for (int gt = 0; gt < 4; ++gt)                         \
                xg[gt] = __builtin_amdgcn_mfma_f32_16x16x32_bf16(af_[kt], wfx[gt][kt], xg[gt], 0, 0, 0); \
    } while (0)

    XBLOCK(0);   // xg for superstep 0 (t = 0..3); reads slots 0-3, no hazard
                 // with iter-0 staging (targets slot 5)

    // OFF is a literal 0..3: parity/slot/extract-index all compile-time.
    // h-MFMA chain takes C = xg[gt] directly (D != C, xg preserved); row
    // quad*4+r holds xg(t_s+r) + hpart(sample quad) -> elem OFF is gates(t).
    // Staging: write x(t+5) from the parity register gathered 2 steps ago,
    // then reload that register with the gather for t+7 (consumed at t+2).
    // Token for the gather was ds_read one step ahead into tk (broadcast,
    // drained by the per-step lgkmcnt(0) barrier -> zero added stall).
#define STEP(OFF) do {                                                               \
        const int t  = ts + OFF;                                                     \
        bf16x8 ah_[4];                                                               \
        _Pragma("unroll") for (int kt = 0; kt < 4; ++kt)                             \
            ah_[kt] = *(const bf16x8*)(hf[OFF & 1] + kt * 32);                       \
        floatx4 acc[4];                                                              \
        _Pragma("unroll") for (int gt = 0; gt < 4; ++gt)                             \
            acc[gt] = __builtin_amdgcn_mfma_f32_16x16x32_bf16(ah_[0], wfh[gt][0], xg[gt], 0, 0, 0); \
        _Pragma("unroll") for (int kt = 1; kt < 4; ++kt)                             \
            _Pragma("unroll") for (int gt = 0; gt < 4; ++gt)                         \
                acc[gt] = __builtin_amdgcn_mfma_f32_16x16x32_bf16(ah_[kt], wfh[gt][kt], acc[gt], 0, 0, 0); \
        const float ii = fsig(acc[0][OFF]);                                          \
        const float ff = fsig(acc[1][OFF]);                                          \
        const float g2 = ftanhf(acc[2][OFF]);                                        \
        const float oo = fsig(acc[3][OFF]);                                          \
        c = ff * c + ii * g2;                                                        \
        const float h = oo * ftanhf(c);                                              \
        if (t == tlast) hl = fmaxf(h, 0.0f);                                         \
        *hw[1 - (OFF & 1)] = (__bf16)h;                                              \
        {                                                                            \
            float& er = ((OFF) & 1) ? e1 : e0;   /* compile-time parity pick */      \
            if (t + 5 < SEQ) {   /* stage x(t+5); slot rotation, compile-time OFF */ \
                const int slot = (OFF == 3) ? (4 * g) : (4 * (1 - g) + OFF + 1);     \
                xw[slot * XST] = (__bf16)fmaxf(er, 0.0f);                            \
            }                                                                        \
            if (t + 7 < SEQ)                                                         \
                er = emb[(size_t)tk * DIM + u];  /* gather for x(t+7) */             \
            tk = tkbuf[m * SEQ + (((t + 8) < SEQ) ? (t + 8) : (SEQ - 1))];           \
        }                                                                            \
        if (OFF == 3 && ts + 4 < Lmax) { XBLOCK(1 - g); }                            \
        block_sync_lds();                                                            \
    } while (0)

    for (int ts = 0; ts < Lmax; ts += 4) {
        const int g = (ts >> 2) & 1;
        STEP(0); STEP(1); STEP(2); STEP(3);
    }
#undef STEP
#undef XBLOCK

    // ---- epilogue: out[b] = [relu(h_last) | onehot] @ linW^T + linb ----
    hlbuf[quad * HID + uu] = hl;
    __syncthreads();
    if (tid < 2 * BQ) {
        const int mm = tid >> 1, kk = tid & 1;
        const int bb = bid * BQ + mm;
        float a2 = linb[kk];
        for (int q = 0; q < HID; ++q)
            a2 += hlbuf[mm * HID + q] * linW[kk * FEAT + q];
        for (int o = 0; o < NOPS; ++o)
            a2 += onehot[bb * NOPS + o] * linW[kk * FEAT + HID + o];
        out[bb * 2 + kk] = a2;
    }
}

extern "C" void kernel_launch(void* const* d_in, const int* in_sizes, int n_in,
                              void* d_out, int out_size, void* d_ws, size_t ws_size,
                              hipStream_t stream) {
    const int*   tokens  = (const int*)d_in[0];
    const int*   lengths = (const int*)d_in[1];
    const float* onehot  = (const float*)d_in[2];
    const float* emb     = (const float*)d_in[3];
    const float* Wih     = (const float*)d_in[4];
    const float* Whh     = (const float*)d_in[5];
    const float* bih     = (const float*)d_in[6];
    const float* bhh     = (const float*)d_in[7];
    const float* h0      = (const float*)d_in[8];
    const float* c0      = (const float*)d_in[9];
    const float* linW    = (const float*)d_in[10];
    const float* linb    = (const float*)d_in[11];
    float* out = (float*)d_out;
    (void)in_sizes; (void)n_in; (void)out_size; (void)d_ws; (void)ws_size;

    lstm_fused<<<dim3(NB / BQ), dim3(512), 0, stream>>>(
        tokens, lengths, onehot, emb, Wih, Whh, bih, bhh, h0, c0, linW, linb, out);
}

// Round 2
// 445.618 us; speedup vs baseline: 1.2716x; 1.1650x over previous
//
#include <hip/hip_runtime.h>
#include <hip/hip_bf16.h>

// Problem constants
#define NB    1024   // batch
#define SEQ   512    // max seq len
#define DIM   128    // embedding dim (D)
#define HID   128    // hidden (H)
#define NOPS  16     // OPS
#define FEAT  144    // H + OPS
#define BQ    4      // samples per workgroup
#define AST   144    // sample stride inside a slot (bf16): breaks pow-2 bank strides
#define XST   578    // x slot stride (bf16) = 289 dwords, odd mod 32 -> ~2-way frag reads

typedef __bf16 bf16x8 __attribute__((ext_vector_type(8)));
typedef float  floatx4 __attribute__((ext_vector_type(4)));

// R6: activations via raw v_exp_f32 + v_rcp_f32. The previous
// 1.0f/(1.0f+__expf(..)) form compiled to the IEEE div sequence
// (v_div_scale/newton/v_div_fmas/v_div_fixup, ~10 insts, ~35 cy dep latency)
// five times per step, all on the serial gate->h chain. rcp is ~1 ulp --
// invisible at our absmax.
#define LOG2E 1.4426950408889634f
__device__ __forceinline__ float fsig(float x) {
    return __builtin_amdgcn_rcpf(1.0f + __builtin_amdgcn_exp2f(-LOG2E * x));
}
__device__ __forceinline__ float ftanhf(float x) {
    return 2.0f * __builtin_amdgcn_rcpf(1.0f + __builtin_amdgcn_exp2f(-2.0f * LOG2E * x)) - 1.0f;
}

// LDS-only barrier: drains lgkmcnt (all cross-wave traffic is LDS), leaves
// global gathers in flight.
__device__ __forceinline__ void block_sync_lds() {
    asm volatile("s_waitcnt lgkmcnt(0)\n\ts_barrier" ::: "memory");
}

// One WG = 512 threads (8 waves) owns BQ=4 samples. Wave w owns unit-chunk w
// for all 4 gate types (gates consumed in-register). 4-STEP X-PACKING: one
// MFMA block per superstep computes x-gates for 4 samples x 4 timesteps
// (A row = sample*4 + off); C/D row quad*4+r -> x-gate(sample=quad, ts+r, uu)
// lands in lane (quad,lrow) reg r. In-loop serial MFMAs are h-part only,
// fed C=xg directly. 8 rotating x-slots; one LDS barrier per step; h
// double-buffered by step parity (compile-time via 4x unroll).
//
// R5: tokens staged to LDS once; embedding gather prefetch 2 steps deep via
// parity pair e0/e1 (compile-time OFF&1 pick).
// R6 (this round): SPLIT-K h-MFMA -- two parallel 2-deep chains per gate
// (kt 0-1 with C=xg, kt 2-3 with C=0, scalar add at extraction) instead of
// one 4-deep chain: halves the MFMA dependency latency on the serial path.
__global__ __launch_bounds__(512, 2)
void lstm_fused(const int* __restrict__ tokens, const int* __restrict__ lengths,
                const float* __restrict__ onehot, const float* __restrict__ emb,
                const float* __restrict__ Wih, const float* __restrict__ Whh,
                const float* __restrict__ bih, const float* __restrict__ bhh,
                const float* __restrict__ h0, const float* __restrict__ c0,
                const float* __restrict__ linW, const float* __restrict__ linb,
                float* __restrict__ out)
{
    __shared__ __align__(16) __bf16 xbuf[8 * XST];        // 8 rotating x slots
    __shared__ __align__(16) __bf16 hbuf[2 * BQ * AST];   // h, parity by t&1
    __shared__ __align__(16) float  hlbuf[BQ * HID];
    __shared__ __align__(16) int    tkbuf[BQ * SEQ];      // all tokens for the 4 samples

    const int tid  = threadIdx.x;
    const int wave = tid >> 6;
    const int lane = tid & 63;
    const int quad = lane >> 4;
    const int lrow = lane & 15;
    const int bid  = blockIdx.x;

    // ---- Weight B-fragments in registers (loaded once). ----
    // B-layout (16x16x32): lane holds B[k=quad*8+j][n=lrow].
    bf16x8 wfx[4][4], wfh[4][4];
#pragma unroll
    for (int gt = 0; gt < 4; ++gt) {
        const int g = gt * 128 + wave * 16 + lrow;
#pragma unroll
        for (int kt = 0; kt < 4; ++kt) {
            const float* sx = Wih + g * DIM + kt * 32 + quad * 8;
            const float* sh = Whh + g * HID + kt * 32 + quad * 8;
            float4 a = *(const float4*)(sx);
            float4 b = *(const float4*)(sx + 4);
            bf16x8 v;
            v[0] = (__bf16)a.x; v[1] = (__bf16)a.y; v[2] = (__bf16)a.z; v[3] = (__bf16)a.w;
            v[4] = (__bf16)b.x; v[5] = (__bf16)b.y; v[6] = (__bf16)b.z; v[7] = (__bf16)b.w;
            wfx[gt][kt] = v;
            a = *(const float4*)(sh);
            b = *(const float4*)(sh + 4);
            v[0] = (__bf16)a.x; v[1] = (__bf16)a.y; v[2] = (__bf16)a.z; v[3] = (__bf16)a.w;
            v[4] = (__bf16)b.x; v[5] = (__bf16)b.y; v[6] = (__bf16)b.z; v[7] = (__bf16)b.w;
            wfh[gt][kt] = v;
        }
    }

    // ---- Per-lane state: sample = quad, unit = uu = wave*16 + lrow ----
    const int uu = wave * 16 + lrow;
    const int bq = bid * BQ + quad;
    int lenq = lengths[bq]; if (lenq < 1) lenq = 1;
    const int tlast = lenq - 1;

    int Lmax = 0;
#pragma unroll
    for (int s2 = 0; s2 < BQ; ++s2) {
        int l2 = lengths[bid * BQ + s2]; if (l2 < 1) l2 = 1;
        Lmax = (l2 > Lmax) ? l2 : Lmax;
    }

    // persistent bias C-registers: accx chains start from these (no splats)
    floatx4 biasC[4];
#pragma unroll
    for (int gt = 0; gt < 4; ++gt) {
        const float bgt = bih[gt * 128 + uu] + bhh[gt * 128 + uu];
        floatx4 a0 = {bgt, bgt, bgt, bgt};
        biasC[gt] = a0;
    }

    float c  = c0[uu];
    float hl = 0.0f;

    // ---- Staging thread layout: m = tid>>7 (sample), u = tid&127 (unit) ----
    const int m  = tid >> 7;
    const int u  = tid & 127;
    const int bm = bid * BQ + m;
    const int sm = m * AST + u;

    // Stage ALL tokens for this WG's 4 samples into LDS (one int4 / thread,
    // fully coalesced). Removes the per-step global token load from the
    // token->emb dependent chain.
    {
        const int4 tv = *(const int4*)(tokens + (size_t)bid * (BQ * SEQ) + tid * 4);
        *(int4*)(&tkbuf[tid * 4]) = tv;
    }

    hbuf[sm] = (__bf16)h0[u];
    const int* tokm = tokens + (size_t)bm * SEQ;
#pragma unroll
    for (int k = 0; k <= 4; ++k) {   // stage x(0..4) into slots 0..4
        float ek = emb[(size_t)tokm[k] * DIM + u];
        xbuf[k * XST + sm] = (__bf16)fmaxf(ek, 0.0f);
    }
    // gather pipeline, 2 steps deep: e0 feeds x(5) at step 0, e1 feeds x(6)
    // at step 1; tk holds token for step 0's gather (x(7)).
    float e0 = emb[(size_t)tokm[5] * DIM + u];
    float e1 = emb[(size_t)tokm[6] * DIM + u];
    int   tk = tokm[7];

    // frag pointers
    const int xfbase = (lrow & 3) * XST + (lrow >> 2) * AST + quad * 8;
    const __bf16* const xfp[2] = { &xbuf[xfbase], &xbuf[4 * XST + xfbase] };
    const int habase = (lrow >> 2) * AST + quad * 8;
    const __bf16* const hf[2] = { &hbuf[habase], &hbuf[BQ * AST + habase] };
    __bf16* const hw[2] = { &hbuf[quad * AST + uu], &hbuf[BQ * AST + quad * AST + uu] };
    __bf16* const xw = &xbuf[sm];

    __syncthreads();   // x(0..4), h(0), tokens staged

    // xg[gt][r] = bias + x(ts+r)@W_ih^T for (sample quad, unit uu)
    floatx4 xg[4];
#define XBLOCK(G) do {                                                               \
        bf16x8 af_[4];                                                               \
        _Pragma("unroll") for (int kt = 0; kt < 4; ++kt)                             \
            af_[kt] = *(const bf16x8*)(xfp[G] + kt * 32);                            \
        _Pragma("unroll") for (int gt = 0; gt < 4; ++gt)                             \
            xg[gt] = __builtin_amdgcn_mfma_f32_16x16x32_bf16(af_[0], wfx[gt][0], biasC[gt], 0, 0, 0); \
        _Pragma("unroll") for (int kt = 1; kt < 4; ++kt)                             \
            _Pragma("unroll") for (int gt = 0; gt < 4; ++gt)                         \
                xg[gt] = __builtin_amdgcn_mfma_f32_16x16x32_bf16(af_[kt], wfx[gt][kt], xg[gt], 0, 0, 0); \
    } while (0)

    XBLOCK(0);   // xg for superstep 0 (t = 0..3); reads slots 0-3, no hazard
                 // with iter-0 staging (targets slot 5)

    const floatx4 zc = {0.0f, 0.0f, 0.0f, 0.0f};   // C-init for the hi K-half

    // OFF is a literal 0..3: parity/slot/extract-index all compile-time.
    // Split-K h-chain: aL = xg + kt0 + kt1 (2-deep), aH = 0 + kt2 + kt3
    // (2-deep, parallel), gate = aL[OFF] + aH[OFF]. Halves MFMA dep latency
    // vs the old 4-deep chain; xg preserved (D != C).
#define STEP(OFF) do {                                                               \
        const int t  = ts + OFF;                                                     \
        bf16x8 ah_[4];                                                               \
        _Pragma("unroll") for (int kt = 0; kt < 4; ++kt)                             \
            ah_[kt] = *(const bf16x8*)(hf[OFF & 1] + kt * 32);                       \
        floatx4 aL[4], aH[4];                                                        \
        _Pragma("unroll") for (int gt = 0; gt < 4; ++gt)                             \
            aL[gt] = __builtin_amdgcn_mfma_f32_16x16x32_bf16(ah_[0], wfh[gt][0], xg[gt], 0, 0, 0); \
        _Pragma("unroll") for (int gt = 0; gt < 4; ++gt)                             \
            aH[gt] = __builtin_amdgcn_mfma_f32_16x16x32_bf16(ah_[2], wfh[gt][2], zc, 0, 0, 0); \
        _Pragma("unroll") for (int gt = 0; gt < 4; ++gt)                             \
            aL[gt] = __builtin_amdgcn_mfma_f32_16x16x32_bf16(ah_[1], wfh[gt][1], aL[gt], 0, 0, 0); \
        _Pragma("unroll") for (int gt = 0; gt < 4; ++gt)                             \
            aH[gt] = __builtin_amdgcn_mfma_f32_16x16x32_bf16(ah_[3], wfh[gt][3], aH[gt], 0, 0, 0); \
        const float ii = fsig(aL[0][OFF] + aH[0][OFF]);                              \
        const float ff = fsig(aL[1][OFF] + aH[1][OFF]);                              \
        const float g2 = ftanhf(aL[2][OFF] + aH[2][OFF]);                            \
        const float oo = fsig(aL[3][OFF] + aH[3][OFF]);                              \
        c = ff * c + ii * g2;                                                        \
        const float h = oo * ftanhf(c);                                              \
        if (t == tlast) hl = fmaxf(h, 0.0f);                                         \
        *hw[1 - (OFF & 1)] = (__bf16)h;                                              \
        {                                                                            \
            float& er = ((OFF) & 1) ? e1 : e0;   /* compile-time parity pick */      \
            if (t + 5 < SEQ) {   /* stage x(t+5); slot rotation, compile-time OFF */ \
                const int slot = (OFF == 3) ? (4 * g) : (4 * (1 - g) + OFF + 1);     \
                xw[slot * XST] = (__bf16)fmaxf(er, 0.0f);                            \
            }                                                                        \
            if (t + 7 < SEQ)                                                         \
                er = emb[(size_t)tk * DIM + u];  /* gather for x(t+7) */             \
            tk = tkbuf[m * SEQ + (((t + 8) < SEQ) ? (t + 8) : (SEQ - 1))];           \
        }                                                                            \
        if (OFF == 3 && ts + 4 < Lmax) { XBLOCK(1 - g); }                            \
        block_sync_lds();                                                            \
    } while (0)

    for (int ts = 0; ts < Lmax; ts += 4) {
        const int g = (ts >> 2) & 1;
        STEP(0); STEP(1); STEP(2); STEP(3);
    }
#undef STEP
#undef XBLOCK

    // ---- epilogue: out[b] = [relu(h_last) | onehot] @ linW^T + linb ----
    hlbuf[quad * HID + uu] = hl;
    __syncthreads();
    if (tid < 2 * BQ) {
        const int mm = tid >> 1, kk = tid & 1;
        const int bb = bid * BQ + mm;
        float a2 = linb[kk];
        for (int q = 0; q < HID; ++q)
            a2 += hlbuf[mm * HID + q] * linW[kk * FEAT + q];
        for (int o = 0; o < NOPS; ++o)
            a2 += onehot[bb * NOPS + o] * linW[kk * FEAT + HID + o];
        out[bb * 2 + kk] = a2;
    }
}

extern "C" void kernel_launch(void* const* d_in, const int* in_sizes, int n_in,
                              void* d_out, int out_size, void* d_ws, size_t ws_size,
                              hipStream_t stream) {
    const int*   tokens  = (const int*)d_in[0];
    const int*   lengths = (const int*)d_in[1];
    const float* onehot  = (const float*)d_in[2];
    const float* emb     = (const float*)d_in[3];
    const float* Wih     = (const float*)d_in[4];
    const float* Whh     = (const float*)d_in[5];
    const float* bih     = (const float*)d_in[6];
    const float* bhh     = (const float*)d_in[7];
    const float* h0      = (const float*)d_in[8];
    const float* c0      = (const float*)d_in[9];
    const float* linW    = (const float*)d_in[10];
    const float* linb    = (const float*)d_in[11];
    float* out = (float*)d_out;
    (void)in_sizes; (void)n_in; (void)out_size; (void)d_ws; (void)ws_size;

    lstm_fused<<<dim3(NB / BQ), dim3(512), 0, stream>>>(
        tokens, lengths, onehot, emb, Wih, Whh, bih, bhh, h0, c0, linW, linb, out);
}

// Round 4
// 435.331 us; speedup vs baseline: 1.3016x; 1.0236x over previous
//
#include <hip/hip_runtime.h>
#include <hip/hip_bf16.h>

// Problem constants
#define NB    1024   // batch
#define SEQ   512    // max seq len
#define DIM   128    // embedding dim (D)
#define HID   128    // hidden (H)
#define NOPS  16     // OPS
#define FEAT  144    // H + OPS
#define BQ    4      // samples per workgroup
#define AST   144    // sample stride inside a slot (bf16): breaks pow-2 bank strides
#define XST   578    // x slot stride (bf16) = 289 dwords, odd mod 32 -> ~2-way frag reads

typedef __bf16 bf16x8 __attribute__((ext_vector_type(8)));
typedef float  floatx4 __attribute__((ext_vector_type(4)));

// R6: activations via raw v_exp_f32 + v_rcp_f32 (~1 ulp, invisible at absmax).
// R7: bias folded into the exp2 argument: arg = k*aL + (k*aH + k*b) as 2 FMAs
// (replaces add+add+mul, -8cy chain) and frees the 16-reg biasC splat array.
__device__ __forceinline__ float gate_s(float aL, float aH, float ka) {
    const float kS = -1.4426950408889634f;   // -log2(e)
    const float arg = __builtin_fmaf(kS, aL, __builtin_fmaf(kS, aH, ka));
    return __builtin_amdgcn_rcpf(1.0f + __builtin_amdgcn_exp2f(arg));
}
__device__ __forceinline__ float gate_t(float aL, float aH, float ka) {
    const float kT = -2.8853900817779268f;   // -2 log2(e)
    const float arg = __builtin_fmaf(kT, aL, __builtin_fmaf(kT, aH, ka));
    return 2.0f * __builtin_amdgcn_rcpf(1.0f + __builtin_amdgcn_exp2f(arg)) - 1.0f;
}
__device__ __forceinline__ float tanh_c(float x) {
    const float kT = -2.8853900817779268f;
    return 2.0f * __builtin_amdgcn_rcpf(1.0f + __builtin_amdgcn_exp2f(kT * x)) - 1.0f;
}

// LDS-only barrier: drains lgkmcnt (all cross-wave traffic is LDS), leaves
// global gathers in flight.
__device__ __forceinline__ void block_sync_lds() {
    asm volatile("s_waitcnt lgkmcnt(0)\n\ts_barrier" ::: "memory");
}

// One WG = 512 threads (8 waves) owns BQ=4 samples. Wave w owns unit-chunk w
// for all 4 gate types (gates consumed in-register). 4-STEP X-PACKING: one
// MFMA block per superstep computes x-gates for 4 samples x 4 timesteps.
// In-loop serial MFMAs are h-part only, split-K 2-deep (R6), fed C=xg.
// R5: tokens staged to LDS once; deep emb-gather pipeline.
// R7 (this round): schedule restructure around the serial chain --
//   (a) staging (x-write / gather issue / token read) moved to the TOP of the
//       step, into the h ds_read latency shadow; the end-of-step lgkmcnt(0)
//       now covers only the 2-byte h-write.
//   (b) XBLOCK moved off the OFF==3 tail to OFF==0 (matrix pipe idles there
//       during activations). xg double-buffered (ping-pong by 8x unroll, G
//       literal); x staged 8 ahead (slot = 4G+OFF, same 8 slots); e-pipeline
//       4 deep (one reg per OFF, literal select); prologue stages x(0..7).
__global__ __launch_bounds__(512, 2)
void lstm_fused(const int* __restrict__ tokens, const int* __restrict__ lengths,
                const float* __restrict__ onehot, const float* __restrict__ emb,
                const float* __restrict__ Wih, const float* __restrict__ Whh,
                const float* __restrict__ bih, const float* __restrict__ bhh,
                const float* __restrict__ h0, const float* __restrict__ c0,
                const float* __restrict__ linW, const float* __restrict__ linb,
                float* __restrict__ out)
{
    __shared__ __align__(16) __bf16 xbuf[8 * XST];        // 8 rotating x slots
    __shared__ __align__(16) __bf16 hbuf[2 * BQ * AST];   // h, parity by t&1
    __shared__ __align__(16) float  hlbuf[BQ * HID];
    __shared__ __align__(16) int    tkbuf[BQ * SEQ];      // all tokens for the 4 samples

    const int tid  = threadIdx.x;
    const int wave = tid >> 6;
    const int lane = tid & 63;
    const int quad = lane >> 4;
    const int lrow = lane & 15;
    const int bid  = blockIdx.x;

    // ---- Weight B-fragments in registers (loaded once). ----
    // B-layout (16x16x32): lane holds B[k=quad*8+j][n=lrow].
    bf16x8 wfx[4][4], wfh[4][4];
#pragma unroll
    for (int gt = 0; gt < 4; ++gt) {
        const int g = gt * 128 + wave * 16 + lrow;
#pragma unroll
        for (int kt = 0; kt < 4; ++kt) {
            const float* sx = Wih + g * DIM + kt * 32 + quad * 8;
            const float* sh = Whh + g * HID + kt * 32 + quad * 8;
            float4 a = *(const float4*)(sx);
            float4 b = *(const float4*)(sx + 4);
            bf16x8 v;
            v[0] = (__bf16)a.x; v[1] = (__bf16)a.y; v[2] = (__bf16)a.z; v[3] = (__bf16)a.w;
            v[4] = (__bf16)b.x; v[5] = (__bf16)b.y; v[6] = (__bf16)b.z; v[7] = (__bf16)b.w;
            wfx[gt][kt] = v;
            a = *(const float4*)(sh);
            b = *(const float4*)(sh + 4);
            v[0] = (__bf16)a.x; v[1] = (__bf16)a.y; v[2] = (__bf16)a.z; v[3] = (__bf16)a.w;
            v[4] = (__bf16)b.x; v[5] = (__bf16)b.y; v[6] = (__bf16)b.z; v[7] = (__bf16)b.w;
            wfh[gt][kt] = v;
        }
    }

    // ---- Per-lane state: sample = quad, unit = uu = wave*16 + lrow ----
    const int uu = wave * 16 + lrow;
    const int bq = bid * BQ + quad;
    int lenq = lengths[bq]; if (lenq < 1) lenq = 1;
    const int tlast = lenq - 1;

    int Lmax = 0;
#pragma unroll
    for (int s2 = 0; s2 < BQ; ++s2) {
        int l2 = lengths[bid * BQ + s2]; if (l2 < 1) l2 = 1;
        Lmax = (l2 > Lmax) ? l2 : Lmax;
    }

    // per-gate activation-arg constants: karg = k * (bih + bhh)
    const float kS = -1.4426950408889634f;
    const float kT = -2.8853900817779268f;
    const float karg0 = kS * (bih[0 * 128 + uu] + bhh[0 * 128 + uu]);
    const float karg1 = kS * (bih[1 * 128 + uu] + bhh[1 * 128 + uu]);
    const float karg2 = kT * (bih[2 * 128 + uu] + bhh[2 * 128 + uu]);
    const float karg3 = kS * (bih[3 * 128 + uu] + bhh[3 * 128 + uu]);

    float c  = c0[uu];
    float hl = 0.0f;

    // ---- Staging thread layout: m = tid>>7 (sample), u = tid&127 (unit) ----
    const int m  = tid >> 7;
    const int u  = tid & 127;
    const int bm = bid * BQ + m;
    const int sm = m * AST + u;

    // Stage ALL tokens for this WG's 4 samples into LDS (one int4 / thread,
    // fully coalesced).
    {
        const int4 tv = *(const int4*)(tokens + (size_t)bid * (BQ * SEQ) + tid * 4);
        *(int4*)(&tkbuf[tid * 4]) = tv;
    }

    hbuf[sm] = (__bf16)h0[u];
    const int* tokm = tokens + (size_t)bm * SEQ;
#pragma unroll
    for (int k = 0; k < 8; ++k) {   // stage x(0..7) into slots 0..7
        float ek = emb[(size_t)tokm[k] * DIM + u];
        xbuf[k * XST + sm] = (__bf16)fmaxf(ek, 0.0f);
    }
    // gather pipeline, 4 steps deep (one reg per OFF): e(OFF) written at step
    // t (as x(t+8)) then reloaded for step t+4 (as x(t+12)). tk = token for
    // the step-0 reload (x(12)), read one step ahead.
    float e0 = emb[(size_t)tokm[8]  * DIM + u];
    float e1 = emb[(size_t)tokm[9]  * DIM + u];
    float e2 = emb[(size_t)tokm[10] * DIM + u];
    float e3 = emb[(size_t)tokm[11] * DIM + u];
    int   tk = tokm[12];

#define EREG(OFF) ((OFF) == 0 ? e0 : (OFF) == 1 ? e1 : (OFF) == 2 ? e2 : e3)

    // frag pointers
    const int xfbase = (lrow & 3) * XST + (lrow >> 2) * AST + quad * 8;
    const __bf16* const xfp[2] = { &xbuf[xfbase], &xbuf[4 * XST + xfbase] };
    const int habase = (lrow >> 2) * AST + quad * 8;
    const __bf16* const hf[2] = { &hbuf[habase], &hbuf[BQ * AST + habase] };
    __bf16* const hw[2] = { &hbuf[quad * AST + uu], &hbuf[BQ * AST + quad * AST + uu] };
    __bf16* const xw = &xbuf[sm];

    __syncthreads();   // x(0..7), h(0), tokens staged

    const floatx4 zc = {0.0f, 0.0f, 0.0f, 0.0f};   // zero C-init

    // XG[gt][r] = x(ts'+r)@W_ih^T (no bias) for (sample quad, unit uu)
    floatx4 xga[4], xgb[4];
#define XBLOCK(GRP, XGN) do {                                                        \
        bf16x8 af_[4];                                                               \
        _Pragma("unroll") for (int kt = 0; kt < 4; ++kt)                             \
            af_[kt] = *(const bf16x8*)(xfp[GRP] + kt * 32);                          \
        _Pragma("unroll") for (int gt = 0; gt < 4; ++gt)                             \
            XGN[gt] = __builtin_amdgcn_mfma_f32_16x16x32_bf16(af_[0], wfx[gt][0], zc, 0, 0, 0); \
        _Pragma("unroll") for (int kt = 1; kt < 4; ++kt)                             \
            _Pragma("unroll") for (int gt = 0; gt < 4; ++gt)                         \
                XGN[gt] = __builtin_amdgcn_mfma_f32_16x16x32_bf16(af_[kt], wfx[gt][kt], XGN[gt], 0, 0, 0); \
    } while (0)

    XBLOCK(0, xga);      // xg for superstep 0 from slots 0..3
    block_sync_lds();    // slots 0..3 are rewritten starting at step 0 (x(8))

    // G, OFF literals: all slot/parity/extract indexing compile-time.
    // Order: h ds_reads first; staging fills their latency shadow; split-K
    // h-MFMA (2x2-deep, C=XGC, XGC preserved since D!=C); XBLOCK at OFF==0
    // (its MFMAs fill the matrix pipe while activations run); act; h-write;
    // minimal drain + barrier.
#define STEP(G, OFF, XGC, XGN) do {                                                  \
        const int t  = ts + OFF;                                                     \
        bf16x8 ah_[4];                                                               \
        _Pragma("unroll") for (int kt = 0; kt < 4; ++kt)                             \
            ah_[kt] = *(const bf16x8*)(hf[OFF & 1] + kt * 32);                       \
        if (t + 8 < SEQ)   /* stage x(t+8) from the reg gathered 4 steps ago */      \
            xw[(4 * (G) + (OFF)) * XST] = (__bf16)fmaxf(EREG(OFF), 0.0f);            \
        if (t + 12 < SEQ)  /* gather for x(t+12) */                                  \
            EREG(OFF) = emb[(size_t)tk * DIM + u];                                   \
        tk = tkbuf[m * SEQ + (((t + 13) < SEQ) ? (t + 13) : (SEQ - 1))];             \
        floatx4 aL[4], aH[4];                                                        \
        _Pragma("unroll") for (int gt = 0; gt < 4; ++gt)                             \
            aL[gt] = __builtin_amdgcn_mfma_f32_16x16x32_bf16(ah_[0], wfh[gt][0], XGC[gt], 0, 0, 0); \
        _Pragma("unroll") for (int gt = 0; gt < 4; ++gt)                             \
            aH[gt] = __builtin_amdgcn_mfma_f32_16x16x32_bf16(ah_[2], wfh[gt][2], zc, 0, 0, 0); \
        _Pragma("unroll") for (int gt = 0; gt < 4; ++gt)                             \
            aL[gt] = __builtin_amdgcn_mfma_f32_16x16x32_bf16(ah_[1], wfh[gt][1], aL[gt], 0, 0, 0); \
        _Pragma("unroll") for (int gt = 0; gt < 4; ++gt)                             \
            aH[gt] = __builtin_amdgcn_mfma_f32_16x16x32_bf16(ah_[3], wfh[gt][3], aH[gt], 0, 0, 0); \
        if (OFF == 0) { XBLOCK(1 - (G), XGN); }                                      \
        const float ii = gate_s(aL[0][OFF], aH[0][OFF], karg0);                      \
        const float ff = gate_s(aL[1][OFF], aH[1][OFF], karg1);                      \
        const float g2 = gate_t(aL[2][OFF], aH[2][OFF], karg2);                      \
        const float oo = gate_s(aL[3][OFF], aH[3][OFF], karg3);                      \
        c = ff * c + ii * g2;                                                        \
        const float h = oo * tanh_c(c);                                              \
        if (t == tlast) hl = fmaxf(h, 0.0f);                                         \
        *hw[1 - (OFF & 1)] = (__bf16)h;                                              \
        block_sync_lds();                                                            \
    } while (0)

    for (int ts8 = 0; ts8 < Lmax; ts8 += 8) {
        {
            const int ts = ts8;
            STEP(0, 0, xga, xgb); STEP(0, 1, xga, xgb);
            STEP(0, 2, xga, xgb); STEP(0, 3, xga, xgb);
        }
        {
            const int ts = ts8 + 4;
            STEP(1, 0, xgb, xga); STEP(1, 1, xgb, xga);
            STEP(1, 2, xgb, xga); STEP(1, 3, xgb, xga);
        }
    }
#undef STEP
#undef XBLOCK
#undef EREG

    // ---- epilogue: out[b] = [relu(h_last) | onehot] @ linW^T + linb ----
    hlbuf[quad * HID + uu] = hl;
    __syncthreads();
    if (tid < 2 * BQ) {
        const int mm = tid >> 1, kk = tid & 1;
        const int bb = bid * BQ + mm;
        float a2 = linb[kk];
        for (int q = 0; q < HID; ++q)
            a2 += hlbuf[mm * HID + q] * linW[kk * FEAT + q];
        for (int o = 0; o < NOPS; ++o)
            a2 += onehot[bb * NOPS + o] * linW[kk * FEAT + HID + o];
        out[bb * 2 + kk] = a2;
    }
}

extern "C" void kernel_launch(void* const* d_in, const int* in_sizes, int n_in,
                              void* d_out, int out_size, void* d_ws, size_t ws_size,
                              hipStream_t stream) {
    const int*   tokens  = (const int*)d_in[0];
    const int*   lengths = (const int*)d_in[1];
    const float* onehot  = (const float*)d_in[2];
    const float* emb     = (const float*)d_in[3];
    const float* Wih     = (const float*)d_in[4];
    const float* Whh     = (const float*)d_in[5];
    const float* bih     = (const float*)d_in[6];
    const float* bhh     = (const float*)d_in[7];
    const float* h0      = (const float*)d_in[8];
    const float* c0      = (const float*)d_in[9];
    const float* linW    = (const float*)d_in[10];
    const float* linb    = (const float*)d_in[11];
    float* out = (float*)d_out;
    (void)in_sizes; (void)n_in; (void)out_size; (void)d_ws; (void)ws_size;

    lstm_fused<<<dim3(NB / BQ), dim3(512), 0, stream>>>(
        tokens, lengths, onehot, emb, Wih, Whh, bih, bhh, h0, c0, linW, linb, out);
}

// Round 6
// 421.778 us; speedup vs baseline: 1.3435x; 1.0321x over previous
//
#include <hip/hip_runtime.h>
#include <hip/hip_bf16.h>

// Problem constants
#define NB    1024   // batch
#define SEQ   512    // max seq len
#define DIM   128    // embedding dim (D)
#define HID   128    // hidden (H)
#define NOPS  16     // OPS
#define FEAT  144    // H + OPS
#define BQ    4      // samples per workgroup
#define AST   144    // sample stride inside a slot (bf16): breaks pow-2 bank strides
#define XST   578    // x slot stride (bf16) = 289 dwords, odd mod 32 -> ~2-way frag reads
#define TKST  (SEQ + 16)   // token buffer stride: padded so tk read needs no clamp

typedef __bf16 bf16x8 __attribute__((ext_vector_type(8)));
typedef float  floatx4 __attribute__((ext_vector_type(4)));

// R6: activations via raw v_exp_f32 + v_rcp_f32 (~1 ulp, invisible at absmax).
// R7: bias folded into the exp2 argument (2 FMAs replace add+add+mul).
__device__ __forceinline__ float gate_s(float aL, float aH, float ka) {
    const float kS = -1.4426950408889634f;   // -log2(e)
    const float arg = __builtin_fmaf(kS, aL, __builtin_fmaf(kS, aH, ka));
    return __builtin_amdgcn_rcpf(1.0f + __builtin_amdgcn_exp2f(arg));
}
__device__ __forceinline__ float gate_t(float aL, float aH, float ka) {
    const float kT = -2.8853900817779268f;   // -2 log2(e)
    const float arg = __builtin_fmaf(kT, aL, __builtin_fmaf(kT, aH, ka));
    return 2.0f * __builtin_amdgcn_rcpf(1.0f + __builtin_amdgcn_exp2f(arg)) - 1.0f;
}
__device__ __forceinline__ float tanh_c(float x) {
    const float kT = -2.8853900817779268f;
    return 2.0f * __builtin_amdgcn_rcpf(1.0f + __builtin_amdgcn_exp2f(kT * x)) - 1.0f;
}

// LDS-only barrier: drains lgkmcnt (all cross-wave traffic is LDS), leaves
// global gathers in flight.
__device__ __forceinline__ void block_sync_lds() {
    asm volatile("s_waitcnt lgkmcnt(0)\n\ts_barrier" ::: "memory");
}

// One WG = 512 threads (8 waves) owns BQ=4 samples. Wave w owns unit-chunk w
// for all 4 gate types. 4-STEP X-PACKING: x-gates for 4 samples x 4 timesteps
// computed per superstep; in-loop serial MFMAs are h-part only, split-K
// 2-deep (R6), fed C=xg. Tokens staged to LDS once; emb gathers 4 steps deep.
// Step-time model (R4 calibration): ~730 cy/step @ ~1 GHz; chain =
// barrier -> h ds_read (8-wave surge) -> 2-deep MFMA -> act chain -> write.
// R8 (this round):
//   (a) XBLOCK spread into per-step kt-slices (1 ds_read + 4 MFMAs/step,
//       XGN accumulates across the superstep) -- removes the 20-inst burst
//       at OFF==0 and smooths the LDS pipe in the lockstep schedule.
//   (b) h-frag reads issued in consumption order (kt 0,2,1,3) so the first
//       h-MFMA can start on lgkmcnt(3) instead of waiting all four reads.
//   (c) tkbuf padded (stride SEQ+16, zeroed tail) -> unconditional tk read.
__global__ __launch_bounds__(512, 2)
void lstm_fused(const int* __restrict__ tokens, const int* __restrict__ lengths,
                const float* __restrict__ onehot, const float* __restrict__ emb,
                const float* __restrict__ Wih, const float* __restrict__ Whh,
                const float* __restrict__ bih, const float* __restrict__ bhh,
                const float* __restrict__ h0, const float* __restrict__ c0,
                const float* __restrict__ linW, const float* __restrict__ linb,
                float* __restrict__ out)
{
    __shared__ __align__(16) __bf16 xbuf[8 * XST];        // 8 rotating x slots
    __shared__ __align__(16) __bf16 hbuf[2 * BQ * AST];   // h, parity by t&1
    __shared__ __align__(16) float  hlbuf[BQ * HID];
    __shared__ __align__(16) int    tkbuf[BQ * TKST];     // tokens (+16 pad/sample)

    const int tid  = threadIdx.x;
    const int wave = tid >> 6;
    const int lane = tid & 63;
    const int quad = lane >> 4;
    const int lrow = lane & 15;
    const int bid  = blockIdx.x;

    // ---- Weight B-fragments in registers (loaded once). ----
    // B-layout (16x16x32): lane holds B[k=quad*8+j][n=lrow].
    bf16x8 wfx[4][4], wfh[4][4];
#pragma unroll
    for (int gt = 0; gt < 4; ++gt) {
        const int g = gt * 128 + wave * 16 + lrow;
#pragma unroll
        for (int kt = 0; kt < 4; ++kt) {
            const float* sx = Wih + g * DIM + kt * 32 + quad * 8;
            const float* sh = Whh + g * HID + kt * 32 + quad * 8;
            float4 a = *(const float4*)(sx);
            float4 b = *(const float4*)(sx + 4);
            bf16x8 v;
            v[0] = (__bf16)a.x; v[1] = (__bf16)a.y; v[2] = (__bf16)a.z; v[3] = (__bf16)a.w;
            v[4] = (__bf16)b.x; v[5] = (__bf16)b.y; v[6] = (__bf16)b.z; v[7] = (__bf16)b.w;
            wfx[gt][kt] = v;
            a = *(const float4*)(sh);
            b = *(const float4*)(sh + 4);
            v[0] = (__bf16)a.x; v[1] = (__bf16)a.y; v[2] = (__bf16)a.z; v[3] = (__bf16)a.w;
            v[4] = (__bf16)b.x; v[5] = (__bf16)b.y; v[6] = (__bf16)b.z; v[7] = (__bf16)b.w;
            wfh[gt][kt] = v;
        }
    }

    // ---- Per-lane state: sample = quad, unit = uu = wave*16 + lrow ----
    const int uu = wave * 16 + lrow;
    const int bq = bid * BQ + quad;
    int lenq = lengths[bq]; if (lenq < 1) lenq = 1;
    const int tlast = lenq - 1;

    int Lmax = 0;
#pragma unroll
    for (int s2 = 0; s2 < BQ; ++s2) {
        int l2 = lengths[bid * BQ + s2]; if (l2 < 1) l2 = 1;
        Lmax = (l2 > Lmax) ? l2 : Lmax;
    }

    // per-gate activation-arg constants: karg = k * (bih + bhh)
    const float kS = -1.4426950408889634f;
    const float kT = -2.8853900817779268f;
    const float karg0 = kS * (bih[0 * 128 + uu] + bhh[0 * 128 + uu]);
    const float karg1 = kS * (bih[1 * 128 + uu] + bhh[1 * 128 + uu]);
    const float karg2 = kT * (bih[2 * 128 + uu] + bhh[2 * 128 + uu]);
    const float karg3 = kS * (bih[3 * 128 + uu] + bhh[3 * 128 + uu]);

    float c  = c0[uu];
    float hl = 0.0f;

    // ---- Staging thread layout: m = tid>>7 (sample), u = tid&127 (unit) ----
    const int m  = tid >> 7;
    const int u  = tid & 127;
    const int bm = bid * BQ + m;
    const int sm = m * AST + u;

    // Stage ALL tokens for this WG's 4 samples into LDS (one int4 / thread,
    // coalesced src). Padded stride; zero-fill the 16-entry tail.
    {
        const int4 tv = *(const int4*)(tokens + (size_t)bm * SEQ + (tid & 127) * 4);
        *(int4*)(&tkbuf[m * TKST + (tid & 127) * 4]) = tv;
        if (tid < BQ * 16)
            tkbuf[(tid >> 4) * TKST + SEQ + (tid & 15)] = 0;
    }

    hbuf[sm] = (__bf16)h0[u];
    const int* tokm = tokens + (size_t)bm * SEQ;
#pragma unroll
    for (int k = 0; k < 8; ++k) {   // stage x(0..7) into slots 0..7
        float ek = emb[(size_t)tokm[k] * DIM + u];
        xbuf[k * XST + sm] = (__bf16)fmaxf(ek, 0.0f);
    }
    // gather pipeline, 4 steps deep (one reg per OFF): e(OFF) written at step
    // t (as x(t+8)) then reloaded for step t+4 (as x(t+12)). tk = token for
    // the step-0 reload (x(12)), read one step ahead.
    float e0 = emb[(size_t)tokm[8]  * DIM + u];
    float e1 = emb[(size_t)tokm[9]  * DIM + u];
    float e2 = emb[(size_t)tokm[10] * DIM + u];
    float e3 = emb[(size_t)tokm[11] * DIM + u];
    int   tk = tokm[12];

#define EREG(OFF) ((OFF) == 0 ? e0 : (OFF) == 1 ? e1 : (OFF) == 2 ? e2 : e3)

    // frag pointers
    const int xfbase = (lrow & 3) * XST + (lrow >> 2) * AST + quad * 8;
    const __bf16* const xfp[2] = { &xbuf[xfbase], &xbuf[4 * XST + xfbase] };
    const int habase = (lrow >> 2) * AST + quad * 8;
    const __bf16* const hf[2] = { &hbuf[habase], &hbuf[BQ * AST + habase] };
    __bf16* const hw[2] = { &hbuf[quad * AST + uu], &hbuf[BQ * AST + quad * AST + uu] };
    __bf16* const xw = &xbuf[sm];

    __syncthreads();   // x(0..7), h(0), tokens staged

    const floatx4 zc = {0.0f, 0.0f, 0.0f, 0.0f};   // zero C-init

    // XG[gt][r] = x(ts'+r)@W_ih^T (no bias) for (sample quad, unit uu).
    // xga for superstep 0 built in full here (from slots 0..3); thereafter
    // XGN accumulates one kt-slice per step inside STEP.
    floatx4 xga[4], xgb[4];
    {
        bf16x8 af_[4];
#pragma unroll
        for (int kt = 0; kt < 4; ++kt)
            af_[kt] = *(const bf16x8*)(xfp[0] + kt * 32);
#pragma unroll
        for (int gt = 0; gt < 4; ++gt)
            xga[gt] = __builtin_amdgcn_mfma_f32_16x16x32_bf16(af_[0], wfx[gt][0], zc, 0, 0, 0);
#pragma unroll
        for (int kt = 1; kt < 4; ++kt)
#pragma unroll
            for (int gt = 0; gt < 4; ++gt)
                xga[gt] = __builtin_amdgcn_mfma_f32_16x16x32_bf16(af_[kt], wfx[gt][kt], xga[gt], 0, 0, 0);
    }
    block_sync_lds();    // slots 0..3 are rewritten starting at step 0 (x(8))

    // G, OFF literals: all slot/parity/extract indexing compile-time.
    // Per-step order: h-frag reads (kt 0,2,1,3 = consumption order) -> x-slice
    // read -> staging (fills read latency) -> split-K h-MFMA (2x2-deep,
    // C=XGC, preserved since D!=C) -> x-slice MFMAs (XGN += kt=OFF layer,
    // C=zc at OFF==0) -> activations -> h-write -> drain+barrier.
#define STEP(G, OFF, XGC, XGN) do {                                                  \
        const int t  = ts + OFF;                                                     \
        bf16x8 ah0 = *(const bf16x8*)(hf[OFF & 1] + 0 * 32);                         \
        bf16x8 ah2 = *(const bf16x8*)(hf[OFF & 1] + 2 * 32);                         \
        bf16x8 ah1 = *(const bf16x8*)(hf[OFF & 1] + 1 * 32);                         \
        bf16x8 ah3 = *(const bf16x8*)(hf[OFF & 1] + 3 * 32);                         \
        bf16x8 ax_ = *(const bf16x8*)(xfp[1 - (G)] + (OFF) * 32);                    \
        if (t + 8 < SEQ)   /* stage x(t+8) from the reg gathered 4 steps ago */      \
            xw[(4 * (G) + (OFF)) * XST] = (__bf16)fmaxf(EREG(OFF), 0.0f);            \
        if (t + 12 < SEQ)  /* gather for x(t+12) */                                  \
            EREG(OFF) = emb[(size_t)tk * DIM + u];                                   \
        tk = tkbuf[m * TKST + t + 13];                                               \
        floatx4 aL[4], aH[4];                                                        \
        _Pragma("unroll") for (int gt = 0; gt < 4; ++gt)                             \
            aL[gt] = __builtin_amdgcn_mfma_f32_16x16x32_bf16(ah0, wfh[gt][0], XGC[gt], 0, 0, 0); \
        _Pragma("unroll") for (int gt = 0; gt < 4; ++gt)                             \
            aH[gt] = __builtin_amdgcn_mfma_f32_16x16x32_bf16(ah2, wfh[gt][2], zc, 0, 0, 0); \
        _Pragma("unroll") for (int gt = 0; gt < 4; ++gt)                             \
            aL[gt] = __builtin_amdgcn_mfma_f32_16x16x32_bf16(ah1, wfh[gt][1], aL[gt], 0, 0, 0); \
        _Pragma("unroll") for (int gt = 0; gt < 4; ++gt)                             \
            aH[gt] = __builtin_amdgcn_mfma_f32_16x16x32_bf16(ah3, wfh[gt][3], aH[gt], 0, 0, 0); \
        if (OFF == 0) {                                                              \
            _Pragma("unroll") for (int gt = 0; gt < 4; ++gt)                         \
                XGN[gt] = __builtin_amdgcn_mfma_f32_16x16x32_bf16(ax_, wfx[gt][0], zc, 0, 0, 0); \
        } else {                                                                     \
            _Pragma("unroll") for (int gt = 0; gt < 4; ++gt)                         \
                XGN[gt] = __builtin_amdgcn_mfma_f32_16x16x32_bf16(ax_, wfx[gt][OFF], XGN[gt], 0, 0, 0); \
        }                                                                            \
        const float ii = gate_s(aL[0][OFF], aH[0][OFF], karg0);                      \
        const float ff = gate_s(aL[1][OFF], aH[1][OFF], karg1);                      \
        const float g2 = gate_t(aL[2][OFF], aH[2][OFF], karg2);                      \
        const float oo = gate_s(aL[3][OFF], aH[3][OFF], karg3);                      \
        c = ff * c + ii * g2;                                                        \
        const float h = oo * tanh_c(c);                                              \
        if (t == tlast) hl = fmaxf(h, 0.0f);                                         \
        *hw[1 - (OFF & 1)] = (__bf16)h;                                              \
        block_sync_lds();                                                            \
    } while (0)

    for (int ts8 = 0; ts8 < Lmax; ts8 += 8) {
        {
            const int ts = ts8;
            STEP(0, 0, xga, xgb); STEP(0, 1, xga, xgb);
            STEP(0, 2, xga, xgb); STEP(0, 3, xga, xgb);
        }
        {
            const int ts = ts8 + 4;
            STEP(1, 0, xgb, xga); STEP(1, 1, xgb, xga);
            STEP(1, 2, xgb, xga); STEP(1, 3, xgb, xga);
        }
    }
#undef STEP
#undef EREG

    // ---- epilogue: out[b] = [relu(h_last) | onehot] @ linW^T + linb ----
    hlbuf[quad * HID + uu] = hl;
    __syncthreads();
    if (tid < 2 * BQ) {
        const int mm = tid >> 1, kk = tid & 1;
        const int bb = bid * BQ + mm;
        float a2 = linb[kk];
        for (int q = 0; q < HID; ++q)
            a2 += hlbuf[mm * HID + q] * linW[kk * FEAT + q];
        for (int o = 0; o < NOPS; ++o)
            a2 += onehot[bb * NOPS + o] * linW[kk * FEAT + HID + o];
        out[bb * 2 + kk] = a2;
    }
}

extern "C" void kernel_launch(void* const* d_in, const int* in_sizes, int n_in,
                              void* d_out, int out_size, void* d_ws, size_t ws_size,
                              hipStream_t stream) {
    const int*   tokens  = (const int*)d_in[0];
    const int*   lengths = (const int*)d_in[1];
    const float* onehot  = (const float*)d_in[2];
    const float* emb     = (const float*)d_in[3];
    const float* Wih     = (const float*)d_in[4];
    const float* Whh     = (const float*)d_in[5];
    const float* bih     = (const float*)d_in[6];
    const float* bhh     = (const float*)d_in[7];
    const float* h0      = (const float*)d_in[8];
    const float* c0      = (const float*)d_in[9];
    const float* linW    = (const float*)d_in[10];
    const float* linb    = (const float*)d_in[11];
    float* out = (float*)d_out;
    (void)in_sizes; (void)n_in; (void)out_size; (void)d_ws; (void)ws_size;

    lstm_fused<<<dim3(NB / BQ), dim3(512), 0, stream>>>(
        tokens, lengths, onehot, emb, Wih, Whh, bih, bhh, h0, c0, linW, linb, out);
}